// Round 1
// baseline (802.433 us; speedup 1.0000x reference)
//
#include <hip/hip_runtime.h>
#include <hip/hip_bf16.h>

#define T_TOK 2048
#define HIDN  4096
#define NH    32
#define HD    192
#define DRR   64
#define QLORA 1536
#define OLORA 512
#define NG    4

typedef unsigned short u16;
typedef __attribute__((ext_vector_type(8))) short short8;
typedef __attribute__((ext_vector_type(4))) float f32x4;

__device__ __forceinline__ float b2f(u16 u) {
  union { unsigned int u; float f; } x; x.u = ((unsigned int)u) << 16; return x.f;
}
__device__ __forceinline__ u16 f2b(float f) {
  union { float f; unsigned int u; } x; x.f = f;
  unsigned int r = x.u + 0x7fff + ((x.u >> 16) & 1);
  return (u16)(r >> 16);
}

// ---------------- cast f32 -> bf16 ----------------
__global__ __launch_bounds__(256) void cast_f32_bf16(const float* __restrict__ src,
                                                     u16* __restrict__ dst, long n4) {
  long i = (long)blockIdx.x * blockDim.x + threadIdx.x;
  long stride = (long)gridDim.x * blockDim.x;
  for (long j = i; j < n4; j += stride) {
    float4 v = *reinterpret_cast<const float4*>(src + j * 4);
    u16 o0 = f2b(v.x), o1 = f2b(v.y), o2 = f2b(v.z), o3 = f2b(v.w);
    u16* d = dst + j * 4;
    d[0] = o0; d[1] = o1; d[2] = o2; d[3] = o3;
  }
}

// ---------------- GEMM: C[M,N] = A[M,K] * B[N,K]^T (bf16 in, f32 acc) ------
// 128x128 tile, BK=32, 4 waves (2x2), each wave 64x64 via 4x4 16x16x32 MFMA.
template <bool OUT_BF16>
__global__ __launch_bounds__(256)
void gemm_bt(const u16* __restrict__ A, const u16* __restrict__ B,
             void* __restrict__ Cout, int M, int N, int K,
             int lda, int ldb, int ldc,
             long a_goff, long b_goff, long c_goff) {
  A += (long)blockIdx.z * a_goff;
  B += (long)blockIdx.z * b_goff;
  __shared__ u16 As[128 * 40];
  __shared__ u16 Bs[128 * 40];
  const int tid = threadIdx.x;
  const int lane = tid & 63;
  const int wave = tid >> 6;
  const int lg = lane >> 4, lr = lane & 15;
  const int wm = (wave >> 1) * 64, wn = (wave & 1) * 64;
  const int m0 = blockIdx.x * 128, n0 = blockIdx.y * 128;
  const int srow = tid >> 1, skh = (tid & 1) * 16;

  f32x4 acc[4][4];
#pragma unroll
  for (int a = 0; a < 4; a++)
#pragma unroll
    for (int b = 0; b < 4; b++) acc[a][b] = f32x4{0.f, 0.f, 0.f, 0.f};

  const u16* pa = A + (long)(m0 + srow) * lda + skh;
  const u16* pb = B + (long)(n0 + srow) * ldb + skh;
  const bool bvalid = (n0 + srow) < N;
  short8* asd = reinterpret_cast<short8*>(&As[srow * 40 + skh]);
  short8* bsd = reinterpret_cast<short8*>(&Bs[srow * 40 + skh]);

  for (int k0 = 0; k0 < K; k0 += 32) {
    short8 a0 = *reinterpret_cast<const short8*>(pa + k0);
    short8 a1 = *reinterpret_cast<const short8*>(pa + k0 + 8);
    short8 b0 = {}, b1 = {};
    if (bvalid) {
      b0 = *reinterpret_cast<const short8*>(pb + k0);
      b1 = *reinterpret_cast<const short8*>(pb + k0 + 8);
    }
    __syncthreads();
    asd[0] = a0; asd[1] = a1;
    bsd[0] = b0; bsd[1] = b1;
    __syncthreads();
    short8 af[4], bf[4];
#pragma unroll
    for (int i = 0; i < 4; i++)
      af[i] = *reinterpret_cast<const short8*>(&As[(wm + i * 16 + lr) * 40 + lg * 8]);
#pragma unroll
    for (int i = 0; i < 4; i++)
      bf[i] = *reinterpret_cast<const short8*>(&Bs[(wn + i * 16 + lr) * 40 + lg * 8]);
#pragma unroll
    for (int mi = 0; mi < 4; mi++)
#pragma unroll
      for (int ni = 0; ni < 4; ni++)
        acc[mi][ni] = __builtin_amdgcn_mfma_f32_16x16x32_bf16(af[mi], bf[ni], acc[mi][ni], 0, 0, 0);
  }

  const long cbase = (long)blockIdx.z * c_goff;
#pragma unroll
  for (int mi = 0; mi < 4; mi++) {
#pragma unroll
    for (int ni = 0; ni < 4; ni++) {
      int col = n0 + wn + ni * 16 + lr;
      if (col < N) {
#pragma unroll
        for (int i = 0; i < 4; i++) {
          int row = m0 + wm + mi * 16 + lg * 4 + i;
          float v = acc[mi][ni][i];
          if constexpr (OUT_BF16)
            reinterpret_cast<u16*>(Cout)[cbase + (long)row * ldc + col] = f2b(v);
          else
            reinterpret_cast<float*>(Cout)[cbase + (long)row * ldc + col] = v;
        }
      }
    }
  }
}

// ---------------- RMSNorm rows of [2048,1536] bf16 in-place, weighted ------
__global__ __launch_bounds__(256)
void rmsnorm_rows(u16* __restrict__ buf, const float* __restrict__ w) {
  const int row = blockIdx.x;
  u16* p = buf + (long)row * QLORA;
  const int tid = threadIdx.x;
  float v[6];
  float ss = 0.f;
#pragma unroll
  for (int j = 0; j < 6; j++) { v[j] = b2f(p[tid + j * 256]); ss += v[j] * v[j]; }
#pragma unroll
  for (int m = 1; m < 64; m <<= 1) ss += __shfl_xor(ss, m);
  __shared__ float red[4];
  if ((tid & 63) == 0) red[tid >> 6] = ss;
  __syncthreads();
  ss = red[0] + red[1] + red[2] + red[3];
  float rinv = rsqrtf(ss * (1.0f / QLORA) + 1e-6f);
#pragma unroll
  for (int j = 0; j < 6; j++) p[tid + j * 256] = f2b(v[j] * rinv * w[tid + j * 256]);
}

// ---------------- per-(t,h) RMSNorm (unweighted) + RoPE, in-place ----------
__global__ __launch_bounds__(64)
void qnorm_rope(u16* __restrict__ q, const int* __restrict__ pos,
                const float* __restrict__ rc, const float* __restrict__ rs) {
  const int t = blockIdx.x, h = blockIdx.y;
  u16* p = q + (long)t * (NH * HD) + h * HD;
  const int lane = threadIdx.x;
  float v0 = b2f(p[lane]), v1 = b2f(p[lane + 64]), v2 = b2f(p[lane + 128]);
  float ss = v0 * v0 + v1 * v1 + v2 * v2;
#pragma unroll
  for (int m = 1; m < 64; m <<= 1) ss += __shfl_xor(ss, m);
  float rinv = rsqrtf(ss * (1.0f / HD) + 1e-6f);
  v0 *= rinv; v1 *= rinv; v2 *= rinv;
  float partner = __shfl_xor(v2, 1);
  int pp = pos[t];
  int j = lane >> 1;
  float c = rc[pp * 32 + j], s = rs[pp * 32 + j];
  float r = ((lane & 1) == 0) ? (v2 * c - partner * s) : (partner * s + v2 * c);
  p[lane] = f2b(v0); p[lane + 64] = f2b(v1); p[lane + 128] = f2b(r);
}

// ---------------- kv RMSNorm (weighted) + RoPE, in-place -------------------
__global__ __launch_bounds__(64)
void kvnorm_rope(u16* __restrict__ kv, const float* __restrict__ w,
                 const int* __restrict__ pos,
                 const float* __restrict__ rc, const float* __restrict__ rs) {
  const int t = blockIdx.x;
  u16* p = kv + (long)t * HD;
  const int lane = threadIdx.x;
  float v0 = b2f(p[lane]), v1 = b2f(p[lane + 64]), v2 = b2f(p[lane + 128]);
  float ss = v0 * v0 + v1 * v1 + v2 * v2;
#pragma unroll
  for (int m = 1; m < 64; m <<= 1) ss += __shfl_xor(ss, m);
  float rinv = rsqrtf(ss * (1.0f / HD) + 1e-6f);
  v0 *= rinv * w[lane]; v1 *= rinv * w[lane + 64]; v2 *= rinv * w[lane + 128];
  float partner = __shfl_xor(v2, 1);
  int pp = pos[t];
  int j = lane >> 1;
  float c = rc[pp * 32 + j], s = rs[pp * 32 + j];
  float r = ((lane & 1) == 0) ? (v2 * c - partner * s) : (partner * s + v2 * c);
  p[lane] = f2b(v0); p[lane + 64] = f2b(v1); p[lane + 128] = f2b(r);
}

// ---------------- flash attention: 1 wave = 16 q rows x 1 head -------------
__global__ __launch_bounds__(64)
void attn(const u16* __restrict__ q, const u16* __restrict__ kv,
          const float* __restrict__ sink, u16* __restrict__ out) {
  const int qb = blockIdx.x, h = blockIdx.y;
  const int q0 = qb * 16;
  const int lane = threadIdx.x;
  const int lg = lane >> 4, lr = lane & 15;
  __shared__ u16 P[16 * 32];

  short8 qf[6];
#pragma unroll
  for (int c = 0; c < 6; c++)
    qf[c] = *reinterpret_cast<const short8*>(q + (long)(q0 + lr) * (NH * HD) + h * HD + c * 32 + lg * 8);

  f32x4 acc[12];
#pragma unroll
  for (int c = 0; c < 12; c++) acc[c] = f32x4{0.f, 0.f, 0.f, 0.f};
  float mr[4], lrow[4];
  const float sk = sink[h];
#pragma unroll
  for (int i = 0; i < 4; i++) { mr[i] = sk; lrow[i] = 1.0f; }
  const float scale = 0.07216878364870323f;  // 192^-0.5
  const int s_end = q0 + 16;

  for (int s0 = 0; s0 < s_end; s0 += 32) {
    f32x4 sc[2];
#pragma unroll
    for (int sub = 0; sub < 2; sub++) {
      int c0 = s0 + sub * 16;
      f32x4 v = f32x4{0.f, 0.f, 0.f, 0.f};
      if (c0 < s_end) {
#pragma unroll
        for (int c = 0; c < 6; c++) {
          short8 kf = *reinterpret_cast<const short8*>(kv + (long)(c0 + lr) * HD + c * 32 + lg * 8);
          v = __builtin_amdgcn_mfma_f32_16x16x32_bf16(qf[c], kf, v, 0, 0, 0);
        }
        int scol = c0 + lr;
#pragma unroll
        for (int i = 0; i < 4; i++) {
          int qrow = q0 + lg * 4 + i;
          v[i] = (scol <= qrow) ? v[i] * scale : -__builtin_inff();
        }
      } else {
#pragma unroll
        for (int i = 0; i < 4; i++) v[i] = -__builtin_inff();
      }
      sc[sub] = v;
    }
    float pr[2][4];
#pragma unroll
    for (int i = 0; i < 4; i++) {
      float t = fmaxf(sc[0][i], sc[1][i]);
#pragma unroll
      for (int m = 1; m < 16; m <<= 1) t = fmaxf(t, __shfl_xor(t, m));
      float mn = fmaxf(mr[i], t);
      float f = __expf(mr[i] - mn);
      float p0 = __expf(sc[0][i] - mn);
      float p1 = __expf(sc[1][i] - mn);
      float rsum = p0 + p1;
#pragma unroll
      for (int m = 1; m < 16; m <<= 1) rsum += __shfl_xor(rsum, m);
      lrow[i] = lrow[i] * f + rsum;
      mr[i] = mn;
      pr[0][i] = p0; pr[1][i] = p1;
#pragma unroll
      for (int c = 0; c < 12; c++) acc[c][i] *= f;
    }
#pragma unroll
    for (int sub = 0; sub < 2; sub++)
#pragma unroll
      for (int i = 0; i < 4; i++)
        P[(lg * 4 + i) * 32 + sub * 16 + lr] = f2b(pr[sub][i]);
    __syncthreads();
    short8 pf = *reinterpret_cast<const short8*>(&P[lr * 32 + lg * 8]);
#pragma unroll
    for (int c = 0; c < 12; c++) {
      short8 vf;
#pragma unroll
      for (int i = 0; i < 8; i++)
        reinterpret_cast<u16*>(&vf)[i] = kv[(long)(s0 + lg * 8 + i) * HD + c * 16 + lr];
      acc[c] = __builtin_amdgcn_mfma_f32_16x16x32_bf16(pf, vf, acc[c], 0, 0, 0);
    }
    __syncthreads();
  }

#pragma unroll
  for (int c = 0; c < 12; c++)
#pragma unroll
    for (int i = 0; i < 4; i++) {
      int qrow = q0 + lg * 4 + i;
      out[(long)qrow * (NH * HD) + h * HD + c * 16 + lr] = f2b(acc[c][i] / lrow[i]);
    }
}

// ---------------------------------------------------------------------------
extern "C" void kernel_launch(void* const* d_in, const int* in_sizes, int n_in,
                              void* d_out, int out_size, void* d_ws, size_t ws_size,
                              hipStream_t stream) {
  const float* x    = (const float*)d_in[0];
  const int* pos    = (const int*)d_in[1];
  const float* wq_a = (const float*)d_in[2];
  const float* q_nw = (const float*)d_in[3];
  const float* wq_b = (const float*)d_in[4];
  const float* wkv  = (const float*)d_in[5];
  const float* kvnw = (const float*)d_in[6];
  const float* sink = (const float*)d_in[7];
  const float* wo_a = (const float*)d_in[8];
  const float* wo_b = (const float*)d_in[9];
  const float* rcos = (const float*)d_in[10];
  const float* rsin = (const float*)d_in[11];
  float* y = (float*)d_out;

  char* ws = (char*)d_ws;
  size_t off = 0;
  auto alloc = [&](size_t bytes) -> void* {
    void* p = ws + off;
    off += (bytes + 255) & ~(size_t)255;
    return p;
  };
  u16* xb   = (u16*)alloc((size_t)T_TOK * HIDN * 2);
  u16* wqab = (u16*)alloc((size_t)QLORA * HIDN * 2);
  u16* wqbb = (u16*)alloc((size_t)NH * HD * QLORA * 2);
  u16* wkvb = (u16*)alloc((size_t)HD * HIDN * 2);
  u16* woab = (u16*)alloc((size_t)NG * OLORA * 1536 * 2);
  u16* wobb = (u16*)alloc((size_t)HIDN * NG * OLORA * 2);
  u16* t1   = (u16*)alloc((size_t)T_TOK * QLORA * 2);
  u16* qn   = (u16*)alloc((size_t)T_TOK * NH * HD * 2);
  u16* kvb  = (u16*)alloc((size_t)T_TOK * HD * 2);
  u16* ao   = (u16*)alloc((size_t)T_TOK * NH * HD * 2);
  u16* olow = (u16*)alloc((size_t)T_TOK * NG * OLORA * 2);

  auto cast = [&](const float* s, u16* d, long n) {
    long n4 = n / 4;
    long blocks = (n4 + 255) / 256;
    if (blocks > 2048) blocks = 2048;
    hipLaunchKernelGGL(cast_f32_bf16, dim3((int)blocks), dim3(256), 0, stream, s, d, n4);
  };
  cast(x, xb, (long)T_TOK * HIDN);
  cast(wq_a, wqab, (long)QLORA * HIDN);
  cast(wq_b, wqbb, (long)NH * HD * QLORA);
  cast(wkv, wkvb, (long)HD * HIDN);
  cast(wo_a, woab, (long)NG * OLORA * 1536);
  cast(wo_b, wobb, (long)HIDN * NG * OLORA);

  // GEMM1: t1[2048,1536] = xb @ wq_a^T
  hipLaunchKernelGGL((gemm_bt<true>), dim3(16, 12, 1), dim3(256), 0, stream,
                     xb, wqab, (void*)t1, 2048, 1536, 4096, 4096, 4096, 1536, 0L, 0L, 0L);
  hipLaunchKernelGGL(rmsnorm_rows, dim3(2048), dim3(256), 0, stream, t1, q_nw);
  // GEMM2: qn[2048,6144] = t1 @ wq_b^T
  hipLaunchKernelGGL((gemm_bt<true>), dim3(16, 48, 1), dim3(256), 0, stream,
                     t1, wqbb, (void*)qn, 2048, 6144, 1536, 1536, 1536, 6144, 0L, 0L, 0L);
  hipLaunchKernelGGL(qnorm_rope, dim3(2048, 32), dim3(64), 0, stream, qn, pos, rcos, rsin);
  // GEMM3: kvb[2048,192] = xb @ wkv^T
  hipLaunchKernelGGL((gemm_bt<true>), dim3(16, 2, 1), dim3(256), 0, stream,
                     xb, wkvb, (void*)kvb, 2048, 192, 4096, 4096, 4096, 192, 0L, 0L, 0L);
  hipLaunchKernelGGL(kvnorm_rope, dim3(2048), dim3(64), 0, stream, kvb, kvnw, pos, rcos, rsin);
  // attention
  hipLaunchKernelGGL(attn, dim3(128, 32), dim3(64), 0, stream, qn, kvb, sink, ao);
  // GEMM4 (grouped): olow[2048, g*512+512] = ao_g @ wo_a_g^T
  hipLaunchKernelGGL((gemm_bt<true>), dim3(16, 4, 4), dim3(256), 0, stream,
                     ao, woab, (void*)olow, 2048, 512, 1536, 6144, 1536, 2048,
                     1536L, (long)512 * 1536, 512L);
  // GEMM5: y[2048,4096] = olow @ wo_b^T  (f32 out)
  hipLaunchKernelGGL((gemm_bt<false>), dim3(16, 32, 1), dim3(256), 0, stream,
                     olow, wobb, (void*)y, 2048, 4096, 2048, 2048, 2048, 4096, 0L, 0L, 0L);
}